// Round 10
// baseline (384.398 us; speedup 1.0000x reference)
//
#include <hip/hip_runtime.h>
#include <hip/hip_bf16.h>
#include <math.h>

#define BB 8
#define AA 65536
#define CC 80
#define GG 16
#define KK 50
#define NBG (BB*GG)
#define CAP 2048
#define BINS 64
#define NCH 128
#define CHUNK (AA/NCH)   // 512
#define NIOU (NCH*BB)    // 1024 iou blocks / candthr blocks / corr blocks
#define NNEG 1024        // neg-dedicated blocks
// neg work split (R5/R9 verified, k_iou_neg = 73us): dedicated blocks do 26
// float4/thread from t=0; anchor blocks append 14 float4/thread after anchor
// work, so the whole machine streams in steady state.
#define NEGS   262144u             // stride = 1024 blocks * 256 threads
#define NPAIR1 13                  // dedicated: 26 float4/thread
#define NPAIR2 7                   // anchor tail: 14 float4/thread
#define NEG0BASE (26u*NEGS)        // 6815744; tail covers [26S, 40S)

// ws layout (bytes)
#define OFF_ACC   0              // double[2]
#define OFF_T2    16             // float[128]
#define OFF_THR   528            // float[128] (unused)
#define OFF_GMASK 1040           // uint[B*C]
#define OFF_CNT   3600           // int[128]
#define OFF_CCNT  4112           // int[1]
#define OFF_HIST  4128           // uint[128*64]
#define HEAD_WORDS 9224          // (4128+32768)/4
#define HEAD0 1032               // words zeroed by block 0 (everything below HIST)
#define OFF_CANDV 36896          // float[128*CAP]
#define OFF_CANDI 1085472        // int[128*CAP]
#define OFF_CLIST 2134048        // uint list

__global__ void k_pre(unsigned* __restrict__ w, const int* __restrict__ labels,
                      unsigned* __restrict__ gmask){
    int tid=threadIdx.x;
    if (blockIdx.x==0){
        for (int i=tid; i<HEAD0; i+=256) w[i]=0u;
        __syncthreads();
        if (tid<NBG){
            int b=tid>>4; int c=labels[tid];
            atomicOr(&gmask[b*CC+c], 1u<<(tid&15));
        }
    } else {
        for (unsigned i=HEAD0+(blockIdx.x-1)*256u+tid; i<HEAD_WORDS; i+=63u*256u) w[i]=0u;
    }
}

#define NEGF4(v) { \
    float l0=v.x,l1=v.y,l2=v.z,l3=v.w; \
    float e0=__expf(l0), e1=__expf(l1), e2=__expf(l2), e3=__expf(l3); \
    float s0=e0*__builtin_amdgcn_rcpf(1.f+e0); \
    float s1=e1*__builtin_amdgcn_rcpf(1.f+e1); \
    float s2=e2*__builtin_amdgcn_rcpf(1.f+e2); \
    float s3=e3*__builtin_amdgcn_rcpf(1.f+e3); \
    fs+=s0*s0*__logf(1.f+e0); \
    fs+=s1*s1*__logf(1.f+e1); \
    fs+=s2*s2*__logf(1.f+e2); \
    fs+=s3*s3*__logf(1.f+e3); }

// fused, fully co-resident (R5/R9 verified: 73us): grid = 2048 blocks = machine
// capacity at 4 waves/block. Type on bit3 of blockIdx (low 3 bits pick the XCD):
//   (x>>3)&1 == 0 -> neg-dedicated stream block (13 pairs)
//   (x>>3)&1 == 1 -> anchor pass, then neg tail (7 pairs)
// NOTE 1: no min-waves launch bound — (256,8) forced VGPR=32 and spilled
//   (909 MB scratch traffic, 5x regression, round 1).
// NOTE 2: all double reductions go to the SINGLE address acc[1] — round 8's
//   accn[64] scatter false-shared cache lines with t2f across 8 XCD L2s and
//   cost +30us on this kernel alone.
__global__ __launch_bounds__(256) void k_iou_neg(const float4* __restrict__ anc4,
        const float4* __restrict__ reg4, const float4* __restrict__ tgt4,
        const float4* __restrict__ lg4,
        unsigned* __restrict__ t2u, unsigned* __restrict__ ghist,
        int* __restrict__ ccnt, unsigned* __restrict__ clist,
        double* __restrict__ acc){
    __shared__ unsigned hist[GG][BINS];
    __shared__ float4 stb[GG];
    __shared__ float sarea[GG];
    __shared__ unsigned st2[GG];
    __shared__ unsigned lbuf[CHUNK];
    __shared__ int lcnt, lbase;
    __shared__ double wsum[4];
    int tid=threadIdx.x;
    int x=blockIdx.x;
    int id=(x>>4)*8+(x&7);   // [0,1024) within each type

    if (((x>>3)&1)==0){
        // ---- neg-dedicated: stream [0, 26S) ----
        double loc=0.0;
        unsigned i0=(unsigned)id*256u+(unsigned)tid;
        for (int gp=0; gp<NPAIR1; ++gp){
            float4 v0=lg4[i0];
            float4 v1=lg4[i0+NEGS];
            i0+=2u*NEGS;
            float fs=0.f;
            NEGF4(v0) NEGF4(v1)
            loc+=(double)fs;
        }
        for (int off=32; off; off>>=1) loc+=__shfl_down(loc,off);
        if ((tid&63)==0) wsum[tid>>6]=loc;
        __syncthreads();
        if (tid==0) atomicAdd(&acc[1],wsum[0]+wsum[1]+wsum[2]+wsum[3]);
        return;
    }

    // ---- anchor pass ----
    int blk=id&(NCH-1), b=id>>7;
    for (int j=tid; j<GG*BINS; j+=256) ((unsigned*)hist)[j]=0u;
    if (tid<GG){
        float4 tb=tgt4[b*GG+tid];
        stb[tid]=tb;
        sarea[tid]=(tb.z-tb.x)*(tb.w-tb.y);
        st2[tid]=0u;
    }
    if (tid==0) lcnt=0;
    __syncthreads();
    float mx[GG];
    #pragma unroll
    for (int g=0; g<GG; ++g) mx[g]=0.f;
    int abase=blk*CHUNK+tid;
    for (int it=0; it<CHUNK/256; ++it){
        int a=abase+it*256;
        float4 an=anc4[a];
        float4 br=reg4[b*AA+a];
        float dcx=an.x+br.x*0.1f*an.z;
        float dcy=an.y+br.y*0.1f*an.w;
        float dw=an.z*__expf(br.z*0.2f);
        float dh=an.w*__expf(br.w*0.2f);
        float dx1=dcx-dw*0.5f, dy1=dcy-dh*0.5f, dx2=dcx+dw*0.5f, dy2=dcy+dh*0.5f;
        float dA=dw*dh;
        float ax1=an.x-an.z*0.5f, ay1=an.y-an.w*0.5f;
        float ax2=an.x+an.z*0.5f, ay2=an.y+an.w*0.5f;
        float aA=an.z*an.w;
        bool emit=false;
        #pragma unroll
        for (int g=0; g<GG; ++g){
            float4 tb=stb[g];
            float tA=sarea[g];
            // decoded-box iou (overlap cull)
            {
                float lx=fmaxf(tb.x,dx1), ly=fmaxf(tb.y,dy1);
                float rx=fminf(tb.z,dx2), ry=fminf(tb.w,dy2);
                float w_=rx-lx, h_=ry-ly;
                if (w_>0.f && h_>0.f){
                    float inter=w_*h_;
                    float iou=inter/(tA+dA-inter);
                    mx[g]=fmaxf(mx[g],iou);
                    if (iou>0.5f) emit=true;
                }
            }
            // anchor-box iou -> histogram (overlap cull)
            {
                float lx=fmaxf(tb.x,ax1), ly=fmaxf(tb.y,ay1);
                float rx=fminf(tb.z,ax2), ry=fminf(tb.w,ay2);
                float w_=rx-lx, h_=ry-ly;
                if (w_>0.f && h_>0.f){
                    float inter=w_*h_;
                    float m=inter/(tA+aA-inter);
                    int bin=min(BINS-1,(int)(m*(float)BINS));
                    atomicAdd(&hist[g][bin],1u);
                }
            }
        }
        if (emit){
            int p=atomicAdd(&lcnt,1);
            lbuf[p]=(unsigned)a;
        }
    }
    #pragma unroll
    for (int g=0; g<GG; ++g){
        float v=mx[g];
        for (int off=32; off; off>>=1) v=fmaxf(v,__shfl_down(v,off));
        if ((tid&63)==0) atomicMax(&st2[g],__float_as_uint(v));
    }
    __syncthreads();
    if (tid<GG) atomicMax(&t2u[b*GG+tid],st2[tid]);
    if (tid==0 && lcnt>0) lbase=atomicAdd(ccnt,lcnt);
    __syncthreads();
    for (int j=tid; j<GG*BINS; j+=256){
        unsigned v=((unsigned*)hist)[j];
        if (v) atomicAdd(&ghist[b*GG*BINS+j],v);
    }
    unsigned bb=(unsigned)b<<16;
    for (int j=tid; j<lcnt; j+=256) clist[lbase+j]=bb|lbuf[j];

    // ---- neg tail: stream [26S, 40S) so the whole machine streams ----
    {
        double loc=0.0;
        unsigned i0=NEG0BASE+(unsigned)id*256u+(unsigned)tid;
        for (int gp=0; gp<NPAIR2; ++gp){
            float4 v0=lg4[i0];
            float4 v1=lg4[i0+NEGS];
            i0+=2u*NEGS;
            float fs=0.f;
            NEGF4(v0) NEGF4(v1)
            loc+=(double)fs;
        }
        for (int off=32; off; off>>=1) loc+=__shfl_down(loc,off);
        if ((tid&63)==0) wsum[tid>>6]=loc;
        __syncthreads();
        if (tid==0) atomicAdd(&acc[1],wsum[0]+wsum[1]+wsum[2]+wsum[3]);
    }
}

// fused back end, full machine (2048 blocks): blocks [0,1024) = candthr
// (byte-identical logic to R9's k_candthr); blocks [1024,2048) = sparse
// correction at 4x the previous block count (R7: corr@256 ~ 25-30us serial;
// @1024 ~ 7us). Both depend only on k_iou_neg outputs — legal concurrency,
// correctness verified by R7's fused variant (absmax 0).
__global__ __launch_bounds__(256) void k_candcorr(const float4* __restrict__ anc4,
        const float4* __restrict__ reg4, const float4* __restrict__ tgt4,
        const float* __restrict__ logits, const unsigned* __restrict__ ghist,
        int* __restrict__ gcnt, float* __restrict__ candv, int* __restrict__ candi,
        const unsigned* __restrict__ gmask, const float* __restrict__ t2f,
        const int* __restrict__ ccnt, const unsigned* __restrict__ clist,
        double* __restrict__ acc){
    __shared__ unsigned hist[GG][BINS];
    __shared__ float4 stb[GG];
    __shared__ float sarea[GG];
    __shared__ float sthr[GG];
    __shared__ double wsum[4];
    int tid=threadIdx.x;
    int x=blockIdx.x;

    if (x>=NIOU){
        // ---- sparse correction (1024 blocks) ----
        int n=*ccnt;
        double loc=0.0;
        for (int i=(x-NIOU)*256+tid; i<n; i+=NIOU*256){
            unsigned key=clist[i];
            int b=key>>16, a=key&0xffff;
            float4 an=anc4[a];
            float4 br=reg4[b*AA+a];
            float dcx=an.x+br.x*0.1f*an.z;
            float dcy=an.y+br.y*0.1f*an.w;
            float dw=an.z*__expf(br.z*0.2f);
            float dh=an.w*__expf(br.w*0.2f);
            float dx1=dcx-dw*0.5f, dy1=dcy-dh*0.5f, dx2=dcx+dw*0.5f, dy2=dcy+dh*0.5f;
            float dA=dw*dh;
            float obp[GG];
            #pragma unroll
            for (int g=0; g<GG; ++g){
                float4 tb=tgt4[b*GG+g];
                float lx=fmaxf(tb.x,dx1), ly=fmaxf(tb.y,dy1);
                float rx=fminf(tb.z,dx2), ry=fminf(tb.w,dy2);
                float w_=fmaxf(rx-lx,0.f), h_=fmaxf(ry-ly,0.f);
                float inter=w_*h_;
                float tA=(tb.z-tb.x)*(tb.w-tb.y);
                float iou=inter/(tA+dA-inter);
                float d=t2f[b*GG+g]-0.5f;
                float inv=(d>0.f)?1.f/d:0.f;
                obp[g]=fminf(fmaxf((iou-0.5f)*inv,0.f),1.f);
            }
            for (int c=0; c<CC; ++c){
                unsigned m=gmask[b*CC+c];
                if (!m) continue;
                float bp=0.f;
                while (m){ unsigned g=(unsigned)__builtin_ctz(m); m&=m-1u; bp=fmaxf(bp,obp[g]); }
                if (bp<=0.f) continue;
                float lg=logits[((size_t)b*AA+(size_t)a)*CC+c];
                float e=__expf(lg);
                float s=e*__builtin_amdgcn_rcpf(1.f+e);
                float xx=s*(1.f-bp);
                float fx=xx*xx*(-__logf(fmaxf(1.f-xx,1e-12f)));
                float fs=s*s*__logf(1.f+e);
                loc+=(double)(fx-fs);
            }
        }
        for (int off=32; off; off>>=1) loc+=__shfl_down(loc,off);
        if ((tid&63)==0) wsum[tid>>6]=loc;
        __syncthreads();
        if (tid==0) atomicAdd(&acc[1],wsum[0]+wsum[1]+wsum[2]+wsum[3]);
        return;
    }

    // ---- candthr (1024 blocks) ----
    int blk=x&(NCH-1), b=x>>7;
    int lane=tid&63, wv=tid>>6;
    for (int j=tid; j<GG*BINS; j+=256) ((unsigned*)hist)[j]=ghist[b*GG*BINS+j];
    if (tid<GG){
        float4 tb=tgt4[b*GG+tid];
        stb[tid]=tb;
        sarea[tid]=(tb.z-tb.x)*(tb.w-tb.y);
    }
    __syncthreads();
    #pragma unroll
    for (int gg=0; gg<4; ++gg){
        int g=wv*4+gg;
        unsigned v=hist[g][lane];
        #pragma unroll
        for (int off=1; off<64; off<<=1){
            unsigned o=__shfl_down(v,off);
            if (lane+off<64) v+=o;
        }
        unsigned long long mask=__ballot(v>=KK);
        int bs = mask ? (63-__clzll(mask)) : 0;
        if (lane==0) sthr[g]=(float)bs;
    }
    __syncthreads();
    int abase=blk*CHUNK+tid;
    for (int it=0; it<CHUNK/256; ++it){
        int a=abase+it*256;
        float4 an=anc4[a];
        float ax1=an.x-an.z*0.5f, ay1=an.y-an.w*0.5f;
        float ax2=an.x+an.z*0.5f, ay2=an.y+an.w*0.5f;
        float aA=an.z*an.w;
        #pragma unroll
        for (int g=0; g<GG; ++g){
            float4 tb=stb[g];
            float m=0.f;
            {
                float lx=fmaxf(tb.x,ax1), ly=fmaxf(tb.y,ay1);
                float rx=fminf(tb.z,ax2), ry=fminf(tb.w,ay2);
                float w_=rx-lx, h_=ry-ly;
                if (w_>0.f && h_>0.f){
                    float inter=w_*h_;
                    m=inter/(sarea[g]+aA-inter);
                }
            }
            bool push=(m>0.f && m*(float)BINS>=sthr[g]);
            unsigned long long msk=__ballot(push);
            if (msk){
                int bg=b*GG+g;
                int n=__popcll(msk);
                int ldr=__ffsll((long long)msk)-1;
                int base=0;
                if (lane==ldr) base=atomicAdd(&gcnt[bg],n);
                base=__shfl(base,ldr);
                if (push){
                    int p=base+(int)__popcll(msk&((1ull<<lane)-1ull));
                    if (p<CAP){ candv[bg*CAP+p]=m; candi[bg*CAP+p]=a; }
                }
            }
        }
    }
}

// 4-wave top-50 + positive bag loss (128 blocks). Each wave selects a local
// top-50 from its quarter of the candidates; wave 0 merges the 4x50 survivors
// (partition-select-merge == global top-k, same comparator: value desc,
// anchor-index asc on ties). Correctness verified in R8 (absmax 0.0).
__global__ __launch_bounds__(256) void k_sel(const float4* __restrict__ anc4,
        const float4* __restrict__ reg4, const float4* __restrict__ tgt4,
        const float* __restrict__ logits, const int* __restrict__ labels,
        const int* __restrict__ gcnt, const float* __restrict__ candv,
        const int* __restrict__ candi, double* __restrict__ acc){
    __shared__ float cv[CAP];
    __shared__ int ci[CAP];
    __shared__ float sv[4*KK];
    __shared__ int si[4*KK];
    int tid=threadIdx.x;
    int bg=blockIdx.x; int b=bg>>4;
    int cnt=gcnt[bg]; if (cnt>CAP) cnt=CAP;
    for (int j=tid; j<cnt; j+=256){ cv[j]=candv[bg*CAP+j]; ci[j]=candi[bg*CAP+j]; }
    __syncthreads();
    int lane=tid&63, w=tid>>6;
    {
        int q=(cnt+3)>>2;
        int lo=w*q; int hi=lo+q; if (hi>cnt) hi=cnt; if (lo>cnt) lo=cnt;
        for (int k=0; k<KK; ++k){
            float bv=-1e30f; int bi=0x7fffffff; int bj=-1;
            for (int j=lo+lane; j<hi; j+=64){
                float v=cv[j]; int ii=ci[j];
                if (v>bv || (v==bv && ii<bi)){ bv=v; bi=ii; bj=j; }
            }
            for (int off=32; off; off>>=1){
                float ov=__shfl_down(bv,off); int oi=__shfl_down(bi,off); int oj=__shfl_down(bj,off);
                if (ov>bv || (ov==bv && oi<bi)){ bv=ov; bi=oi; bj=oj; }
            }
            float wvv=__shfl(bv,0); int wii=__shfl(bi,0); int wjj=__shfl(bj,0);
            if (lane==0){
                sv[w*KK+k]=wvv; si[w*KK+k]=wii;
                if (wvv>-1e29f) cv[wjj]=-1e30f;
            }
        }
    }
    __syncthreads();
    if (tid>=64) return;
    // wave 0: merge 200 entries
    int myA=-1;
    for (int k=0; k<KK; ++k){
        float bv=-1e30f; int bi=0x7fffffff; int bj=-1;
        for (int e=lane; e<4*KK; e+=64){
            float v=sv[e]; int ii=si[e];
            if (v>bv || (v==bv && ii<bi)){ bv=v; bi=ii; bj=e; }
        }
        for (int off=32; off; off>>=1){
            float ov=__shfl_down(bv,off); int oi=__shfl_down(bi,off); int oj=__shfl_down(bj,off);
            if (ov>bv || (ov==bv && oi<bi)){ bv=ov; bi=oi; bj=oj; }
        }
        float wvv=__shfl(bv,0); int wii=__shfl(bi,0); int wjj=__shfl(bj,0);
        if (lane==0 && wvv>-1e29f) sv[wjj]=-1e30f;
        if (lane==k) myA=(wvv>-1e29f)?wii:-1;
    }
    float p=0.f, u=0.f;
    if (lane<KK && myA>=0){
        float4 tb=tgt4[bg];
        int a=myA;
        float4 an=anc4[a];
        int lab=labels[bg];
        float lg=logits[((size_t)b*AA+(size_t)a)*CC+lab];
        float mcp=1.f/(1.f+expf(-lg));
        float gcx=((tb.x+tb.z)*0.5f-an.x)/(0.1f*an.z);
        float gcy=((tb.y+tb.w)*0.5f-an.y)/(0.1f*an.w);
        float gw=logf((tb.z-tb.x)/an.z)/0.2f;
        float gh=logf((tb.w-tb.y)/an.w)/0.2f;
        float4 br=reg4[b*AA+a];
        float v0=gcx-br.x, v1=gcy-br.y, v2=gw-br.z, v3=gh-br.w;
        float s=0.f;
        {float av=fabsf(v0); s+=(av<0.11f)?4.545454545454546f*v0*v0:av-0.055f;}
        {float av=fabsf(v1); s+=(av<0.11f)?4.545454545454546f*v1*v1:av-0.055f;}
        {float av=fabsf(v2); s+=(av<0.11f)?4.545454545454546f*v2*v2:av-0.055f;}
        {float av=fabsf(v3); s+=(av<0.11f)?4.545454545454546f*v3*v3:av-0.055f;}
        float mbp=expf(-(0.75f*s));
        p=mcp*mbp;
        u=1.f/fmaxf(1.f-p,1e-12f);
    }
    float su=u, sp=u*p;
    for (int off=32; off; off>>=1){ su+=__shfl_down(su,off); sp+=__shfl_down(sp,off); }
    if (lane==0) atomicAdd(&acc[0],(double)(-logf(sp/su)));
}

__global__ void k_fin(const double* __restrict__ acc, float* __restrict__ out){
    out[0]=(float)(0.5*acc[0]/128.0);
    out[1]=(float)(0.5*acc[1]/6400.0);
}

extern "C" void kernel_launch(void* const* d_in, const int* in_sizes, int n_in,
                              void* d_out, int out_size, void* d_ws, size_t ws_size,
                              hipStream_t stream){
    const float4* reg4=(const float4*)d_in[0];
    const float*  logits=(const float*)d_in[1];
    const float4* anc4=(const float4*)d_in[2];
    const float4* tgt4=(const float4*)d_in[3];
    const int*    labels=(const int*)d_in[4];
    char* ws=(char*)d_ws;
    double*   acc   =(double*)(ws+OFF_ACC);
    float*    t2f   =(float*)(ws+OFF_T2);
    unsigned* gmask =(unsigned*)(ws+OFF_GMASK);
    int*      gcnt  =(int*)(ws+OFF_CNT);
    int*      ccnt  =(int*)(ws+OFF_CCNT);
    unsigned* ghist =(unsigned*)(ws+OFF_HIST);
    float*    candv =(float*)(ws+OFF_CANDV);
    int*      candi =(int*)(ws+OFF_CANDI);
    unsigned* clist =(unsigned*)(ws+OFF_CLIST);

    k_pre<<<64,256,0,stream>>>((unsigned*)ws,labels,gmask);
    k_iou_neg<<<NNEG+NIOU,256,0,stream>>>(anc4,reg4,tgt4,(const float4*)logits,
                                          (unsigned*)t2f,ghist,ccnt,clist,acc);
    k_candcorr<<<NIOU+NIOU,256,0,stream>>>(anc4,reg4,tgt4,logits,ghist,gcnt,candv,candi,
                                           gmask,t2f,ccnt,clist,acc);
    k_sel<<<NBG,256,0,stream>>>(anc4,reg4,tgt4,logits,labels,gcnt,candv,candi,acc);
    k_fin<<<1,1,0,stream>>>(acc,(float*)d_out);
}

// Round 11
// 313.771 us; speedup vs baseline: 1.2251x; 1.2251x over previous
//
#include <hip/hip_runtime.h>
#include <hip/hip_bf16.h>
#include <math.h>

#define BB 8
#define AA 65536
#define CC 80
#define GG 16
#define KK 50
#define NBG (BB*GG)
#define CAP 2048
#define BINS 64
#define NCH 128
#define CHUNK (AA/NCH)   // 512
#define NIOU (NCH*BB)    // 1024 iou blocks
#define NNEG 1024        // neg-dedicated blocks
// neg work split: dedicated blocks do 26 float4/thread (13 pairs) from t=0;
// anchor blocks append 14 float4/thread (7 pairs) after their anchor work,
// so the whole machine streams in steady state.
#define NEGS   262144u             // stride = 1024 blocks * 256 threads
#define NPAIR1 13                  // dedicated: 26 float4/thread
#define NPAIR2 7                   // anchor tail: 14 float4/thread
#define NEG0BASE (26u*NEGS)        // 6815744; tail covers [26S, 40S)

// ws layout (bytes)
#define OFF_ACC   0              // double[2]
#define OFF_T2    16             // float[128]
#define OFF_THR   528            // float[128] (unused)
#define OFF_GMASK 1040           // uint[B*C]
#define OFF_CNT   3600           // int[128]
#define OFF_CCNT  4112           // int[1]
#define OFF_HIST  4128           // uint[128*64]
#define HEAD_WORDS 9224          // (4128+32768)/4
#define HEAD0 1032               // words zeroed by block 0 (everything below HIST)
#define OFF_CANDV 36896          // float[128*CAP]
#define OFF_CANDI 1085472        // int[128*CAP]
#define OFF_CLIST 2134048        // uint list

// ============================================================================
// SESSION LEDGER (measured, MI355X; reproducibility +-1.5us):
//   R9/R5 (this structure)          : 314.2 / 315.4  <- BEST
//   R0 baseline                     : 342.7
//   composition: ~194us harness ws-poison fills (2x97us @ 87% HBM peak,
//   untouchable) + ~73us k_iou_neg + ~47us back end.
// Measured-worse alternatives (do NOT revisit):
//   - (256,8) launch bound          : VGPR 32, spills, +370us  (R1)
//   - neg/anchor as separate kernels: +31us (lost overlap)     (R6)
//   - {candthr || corr} fusion      : +22 (corr@256), +70 (corr@1024) (R7,R10)
//   - accn[64] slot reduction       : +30us on k_iou_neg (false sharing
//     across XCD L2s; single-address acc[1] atomic is FASTER)  (R8)
//   - candthr @ 2048 blocks, 4-wave top50 bundle: part of +45  (R8)
// ============================================================================

__global__ void k_pre(unsigned* __restrict__ w, const int* __restrict__ labels,
                      unsigned* __restrict__ gmask){
    int tid=threadIdx.x;
    if (blockIdx.x==0){
        for (int i=tid; i<HEAD0; i+=256) w[i]=0u;
        __syncthreads();
        if (tid<NBG){
            int b=tid>>4; int c=labels[tid];
            atomicOr(&gmask[b*CC+c], 1u<<(tid&15));
        }
    } else {
        for (unsigned i=HEAD0+(blockIdx.x-1)*256u+tid; i<HEAD_WORDS; i+=63u*256u) w[i]=0u;
    }
}

#define NEGF4(v) { \
    float l0=v.x,l1=v.y,l2=v.z,l3=v.w; \
    float e0=__expf(l0), e1=__expf(l1), e2=__expf(l2), e3=__expf(l3); \
    float s0=e0*__builtin_amdgcn_rcpf(1.f+e0); \
    float s1=e1*__builtin_amdgcn_rcpf(1.f+e1); \
    float s2=e2*__builtin_amdgcn_rcpf(1.f+e2); \
    float s3=e3*__builtin_amdgcn_rcpf(1.f+e3); \
    fs+=s0*s0*__logf(1.f+e0); \
    fs+=s1*s1*__logf(1.f+e1); \
    fs+=s2*s2*__logf(1.f+e2); \
    fs+=s3*s3*__logf(1.f+e3); }

// fused, fully co-resident: grid = 2048 blocks = machine capacity at 4
// waves/block. Type on bit3 of blockIdx (low 3 bits pick the XCD, so both
// types spread across all 8 XCDs and every CU hosts ~4 of each):
//   (x>>3)&1 == 0 -> neg-dedicated stream block (13 pairs)
//   (x>>3)&1 == 1 -> anchor pass, then neg tail (7 pairs)
// The anchor pass's latency-bound IoU work hides under the neg blocks' memory
// stalls (m114 co-schedule); the tail keeps the whole machine streaming after
// the anchor phase drains.
__global__ __launch_bounds__(256) void k_iou_neg(const float4* __restrict__ anc4,
        const float4* __restrict__ reg4, const float4* __restrict__ tgt4,
        const float4* __restrict__ lg4,
        unsigned* __restrict__ t2u, unsigned* __restrict__ ghist,
        int* __restrict__ ccnt, unsigned* __restrict__ clist,
        double* __restrict__ acc){
    __shared__ unsigned hist[GG][BINS];
    __shared__ float4 stb[GG];
    __shared__ float sarea[GG];
    __shared__ unsigned st2[GG];
    __shared__ unsigned lbuf[CHUNK];
    __shared__ int lcnt, lbase;
    __shared__ double wsum[4];
    int tid=threadIdx.x;
    int x=blockIdx.x;
    int id=(x>>4)*8+(x&7);   // [0,1024) within each type

    if (((x>>3)&1)==0){
        // ---- neg-dedicated: stream [0, 26S) ----
        double loc=0.0;
        unsigned i0=(unsigned)id*256u+(unsigned)tid;
        for (int gp=0; gp<NPAIR1; ++gp){
            float4 v0=lg4[i0];
            float4 v1=lg4[i0+NEGS];
            i0+=2u*NEGS;
            float fs=0.f;
            NEGF4(v0) NEGF4(v1)
            loc+=(double)fs;
        }
        for (int off=32; off; off>>=1) loc+=__shfl_down(loc,off);
        if ((tid&63)==0) wsum[tid>>6]=loc;
        __syncthreads();
        if (tid==0) atomicAdd(&acc[1],wsum[0]+wsum[1]+wsum[2]+wsum[3]);
        return;
    }

    // ---- anchor pass ----
    int blk=id&(NCH-1), b=id>>7;
    for (int j=tid; j<GG*BINS; j+=256) ((unsigned*)hist)[j]=0u;
    if (tid<GG){
        float4 tb=tgt4[b*GG+tid];
        stb[tid]=tb;
        sarea[tid]=(tb.z-tb.x)*(tb.w-tb.y);
        st2[tid]=0u;
    }
    if (tid==0) lcnt=0;
    __syncthreads();
    float mx[GG];
    #pragma unroll
    for (int g=0; g<GG; ++g) mx[g]=0.f;
    int abase=blk*CHUNK+tid;
    for (int it=0; it<CHUNK/256; ++it){
        int a=abase+it*256;
        float4 an=anc4[a];
        float4 br=reg4[b*AA+a];
        float dcx=an.x+br.x*0.1f*an.z;
        float dcy=an.y+br.y*0.1f*an.w;
        float dw=an.z*__expf(br.z*0.2f);
        float dh=an.w*__expf(br.w*0.2f);
        float dx1=dcx-dw*0.5f, dy1=dcy-dh*0.5f, dx2=dcx+dw*0.5f, dy2=dcy+dh*0.5f;
        float dA=dw*dh;
        float ax1=an.x-an.z*0.5f, ay1=an.y-an.w*0.5f;
        float ax2=an.x+an.z*0.5f, ay2=an.y+an.w*0.5f;
        float aA=an.z*an.w;
        bool emit=false;
        #pragma unroll
        for (int g=0; g<GG; ++g){
            float4 tb=stb[g];
            float tA=sarea[g];
            // decoded-box iou (overlap cull)
            {
                float lx=fmaxf(tb.x,dx1), ly=fmaxf(tb.y,dy1);
                float rx=fminf(tb.z,dx2), ry=fminf(tb.w,dy2);
                float w_=rx-lx, h_=ry-ly;
                if (w_>0.f && h_>0.f){
                    float inter=w_*h_;
                    float iou=inter/(tA+dA-inter);
                    mx[g]=fmaxf(mx[g],iou);
                    if (iou>0.5f) emit=true;
                }
            }
            // anchor-box iou -> histogram (overlap cull)
            {
                float lx=fmaxf(tb.x,ax1), ly=fmaxf(tb.y,ay1);
                float rx=fminf(tb.z,ax2), ry=fminf(tb.w,ay2);
                float w_=rx-lx, h_=ry-ly;
                if (w_>0.f && h_>0.f){
                    float inter=w_*h_;
                    float m=inter/(tA+aA-inter);
                    int bin=min(BINS-1,(int)(m*(float)BINS));
                    atomicAdd(&hist[g][bin],1u);
                }
            }
        }
        if (emit){
            int p=atomicAdd(&lcnt,1);
            lbuf[p]=(unsigned)a;
        }
    }
    #pragma unroll
    for (int g=0; g<GG; ++g){
        float v=mx[g];
        for (int off=32; off; off>>=1) v=fmaxf(v,__shfl_down(v,off));
        if ((tid&63)==0) atomicMax(&st2[g],__float_as_uint(v));
    }
    __syncthreads();
    if (tid<GG) atomicMax(&t2u[b*GG+tid],st2[tid]);
    if (tid==0 && lcnt>0) lbase=atomicAdd(ccnt,lcnt);
    __syncthreads();
    for (int j=tid; j<GG*BINS; j+=256){
        unsigned v=((unsigned*)hist)[j];
        if (v) atomicAdd(&ghist[b*GG*BINS+j],v);
    }
    unsigned bb=(unsigned)b<<16;
    for (int j=tid; j<lcnt; j+=256) clist[lbase+j]=bb|lbuf[j];

    // ---- neg tail: stream [26S, 40S) so the whole machine streams ----
    {
        double loc=0.0;
        unsigned i0=NEG0BASE+(unsigned)id*256u+(unsigned)tid;
        for (int gp=0; gp<NPAIR2; ++gp){
            float4 v0=lg4[i0];
            float4 v1=lg4[i0+NEGS];
            i0+=2u*NEGS;
            float fs=0.f;
            NEGF4(v0) NEGF4(v1)
            loc+=(double)fs;
        }
        for (int off=32; off; off>>=1) loc+=__shfl_down(loc,off);
        if ((tid&63)==0) wsum[tid>>6]=loc;
        __syncthreads();
        if (tid==0) atomicAdd(&acc[1],wsum[0]+wsum[1]+wsum[2]+wsum[3]);
    }
}

// threshold from histogram (in-block suffix scan) + candidate collection
__global__ __launch_bounds__(256) void k_candthr(const float4* __restrict__ anc4,
        const float4* __restrict__ tgt4, const unsigned* __restrict__ ghist,
        int* __restrict__ gcnt, float* __restrict__ candv, int* __restrict__ candi){
    __shared__ unsigned hist[GG][BINS];
    __shared__ float4 stb[GG];
    __shared__ float sarea[GG];
    __shared__ float sthr[GG];
    int tid=threadIdx.x, blk=blockIdx.x, b=blockIdx.y;
    int lane=tid&63, wv=tid>>6;
    for (int j=tid; j<GG*BINS; j+=256) ((unsigned*)hist)[j]=ghist[b*GG*BINS+j];
    if (tid<GG){
        float4 tb=tgt4[b*GG+tid];
        stb[tid]=tb;
        sarea[tid]=(tb.z-tb.x)*(tb.w-tb.y);
    }
    __syncthreads();
    #pragma unroll
    for (int gg=0; gg<4; ++gg){
        int g=wv*4+gg;
        unsigned v=hist[g][lane];
        #pragma unroll
        for (int off=1; off<64; off<<=1){
            unsigned o=__shfl_down(v,off);
            if (lane+off<64) v+=o;
        }
        unsigned long long mask=__ballot(v>=KK);
        int bs = mask ? (63-__clzll(mask)) : 0;
        if (lane==0) sthr[g]=(float)bs;
    }
    __syncthreads();
    int abase=blk*CHUNK+tid;
    for (int it=0; it<CHUNK/256; ++it){
        int a=abase+it*256;
        float4 an=anc4[a];
        float ax1=an.x-an.z*0.5f, ay1=an.y-an.w*0.5f;
        float ax2=an.x+an.z*0.5f, ay2=an.y+an.w*0.5f;
        float aA=an.z*an.w;
        #pragma unroll
        for (int g=0; g<GG; ++g){
            float4 tb=stb[g];
            float m=0.f;
            {
                float lx=fmaxf(tb.x,ax1), ly=fmaxf(tb.y,ay1);
                float rx=fminf(tb.z,ax2), ry=fminf(tb.w,ay2);
                float w_=rx-lx, h_=ry-ly;
                if (w_>0.f && h_>0.f){
                    float inter=w_*h_;
                    m=inter/(sarea[g]+aA-inter);
                }
            }
            bool push=(m>0.f && m*(float)BINS>=sthr[g]);
            unsigned long long msk=__ballot(push);
            if (msk){
                int bg=b*GG+g;
                int n=__popcll(msk);
                int ldr=__ffsll((long long)msk)-1;
                int base=0;
                if (lane==ldr) base=atomicAdd(&gcnt[bg],n);
                base=__shfl(base,ldr);
                if (push){
                    int p=base+(int)__popcll(msk&((1ull<<lane)-1ull));
                    if (p<CAP){ candv[bg*CAP+p]=m; candi[bg*CAP+p]=a; }
                }
            }
        }
    }
}

// fused: blocks [0,128) top-50 + positive bag loss; blocks [128,384) correction
// (top50 hides under the heavier correction pass; measured-best arrangement)
__global__ __launch_bounds__(256) void k_selcorr(const float4* __restrict__ anc4,
        const float4* __restrict__ reg4, const float4* __restrict__ tgt4,
        const float* __restrict__ logits, const int* __restrict__ labels,
        const int* __restrict__ gcnt, const float* __restrict__ candv,
        const int* __restrict__ candi, const unsigned* __restrict__ gmask,
        const float* __restrict__ t2f, const int* __restrict__ ccnt,
        const unsigned* __restrict__ clist, double* __restrict__ acc){
    __shared__ float cv[CAP];
    __shared__ int ci[CAP];
    __shared__ double wsum[4];
    int tid=threadIdx.x;
    int x=blockIdx.x;

    if (x>=NBG){
        // ---- sparse correction ----
        int n=*ccnt;
        double loc=0.0;
        for (int i=(x-NBG)*256+tid; i<n; i+=256*256){
            unsigned key=clist[i];
            int b=key>>16, a=key&0xffff;
            float4 an=anc4[a];
            float4 br=reg4[b*AA+a];
            float dcx=an.x+br.x*0.1f*an.z;
            float dcy=an.y+br.y*0.1f*an.w;
            float dw=an.z*__expf(br.z*0.2f);
            float dh=an.w*__expf(br.w*0.2f);
            float dx1=dcx-dw*0.5f, dy1=dcy-dh*0.5f, dx2=dcx+dw*0.5f, dy2=dcy+dh*0.5f;
            float dA=dw*dh;
            float obp[GG];
            #pragma unroll
            for (int g=0; g<GG; ++g){
                float4 tb=tgt4[b*GG+g];
                float lx=fmaxf(tb.x,dx1), ly=fmaxf(tb.y,dy1);
                float rx=fminf(tb.z,dx2), ry=fminf(tb.w,dy2);
                float w_=fmaxf(rx-lx,0.f), h_=fmaxf(ry-ly,0.f);
                float inter=w_*h_;
                float tA=(tb.z-tb.x)*(tb.w-tb.y);
                float iou=inter/(tA+dA-inter);
                float d=t2f[b*GG+g]-0.5f;
                float inv=(d>0.f)?1.f/d:0.f;
                obp[g]=fminf(fmaxf((iou-0.5f)*inv,0.f),1.f);
            }
            for (int c=0; c<CC; ++c){
                unsigned m=gmask[b*CC+c];
                if (!m) continue;
                float bp=0.f;
                while (m){ unsigned g=(unsigned)__builtin_ctz(m); m&=m-1u; bp=fmaxf(bp,obp[g]); }
                if (bp<=0.f) continue;
                float lg=logits[((size_t)b*AA+(size_t)a)*CC+c];
                float e=__expf(lg);
                float s=e*__builtin_amdgcn_rcpf(1.f+e);
                float xx=s*(1.f-bp);
                float fx=xx*xx*(-__logf(fmaxf(1.f-xx,1e-12f)));
                float fs=s*s*__logf(1.f+e);
                loc+=(double)(fx-fs);
            }
        }
        for (int off=32; off; off>>=1) loc+=__shfl_down(loc,off);
        if ((tid&63)==0) wsum[tid>>6]=loc;
        __syncthreads();
        if (tid==0) atomicAdd(&acc[1],wsum[0]+wsum[1]+wsum[2]+wsum[3]);
        return;
    }

    // ---- top-50 + positive bag loss (wave 0 after cooperative load) ----
    int bg=x; int b=bg>>4;
    int cnt=gcnt[bg]; if (cnt>CAP) cnt=CAP;
    for (int j=tid; j<cnt; j+=256){ cv[j]=candv[bg*CAP+j]; ci[j]=candi[bg*CAP+j]; }
    __syncthreads();
    if (tid>=64) return;
    int lane=tid;
    int myA=-1;
    for (int k=0; k<KK; ++k){
        float bv=-1e30f; int bi=0x7fffffff; int bj=-1;
        for (int j=lane; j<cnt; j+=64){
            float v=cv[j]; int ii=ci[j];
            if (v>bv || (v==bv && ii<bi)){ bv=v; bi=ii; bj=j; }
        }
        for (int off=32; off; off>>=1){
            float ov=__shfl_down(bv,off); int oi=__shfl_down(bi,off); int oj=__shfl_down(bj,off);
            if (ov>bv || (ov==bv && oi<bi)){ bv=ov; bi=oi; bj=oj; }
        }
        int wj=__shfl(bj,0); int wi=__shfl(bi,0); float wv=__shfl(bv,0);
        if (wv>-1e29f){
            if (lane==(wj&63)) cv[wj]=-1e30f;
            if (lane==k) myA=wi;
        }
    }
    float p=0.f, u=0.f;
    if (lane<KK && myA>=0){
        float4 tb=tgt4[bg];
        int a=myA;
        float4 an=anc4[a];
        int lab=labels[bg];
        float lg=logits[((size_t)b*AA+(size_t)a)*CC+lab];
        float mcp=1.f/(1.f+expf(-lg));
        float gcx=((tb.x+tb.z)*0.5f-an.x)/(0.1f*an.z);
        float gcy=((tb.y+tb.w)*0.5f-an.y)/(0.1f*an.w);
        float gw=logf((tb.z-tb.x)/an.z)/0.2f;
        float gh=logf((tb.w-tb.y)/an.w)/0.2f;
        float4 br=reg4[b*AA+a];
        float v0=gcx-br.x, v1=gcy-br.y, v2=gw-br.z, v3=gh-br.w;
        float s=0.f;
        {float av=fabsf(v0); s+=(av<0.11f)?4.545454545454546f*v0*v0:av-0.055f;}
        {float av=fabsf(v1); s+=(av<0.11f)?4.545454545454546f*v1*v1:av-0.055f;}
        {float av=fabsf(v2); s+=(av<0.11f)?4.545454545454546f*v2*v2:av-0.055f;}
        {float av=fabsf(v3); s+=(av<0.11f)?4.545454545454546f*v3*v3:av-0.055f;}
        float mbp=expf(-(0.75f*s));
        p=mcp*mbp;
        u=1.f/fmaxf(1.f-p,1e-12f);
    }
    float su=u, sp=u*p;
    for (int off=32; off; off>>=1){ su+=__shfl_down(su,off); sp+=__shfl_down(sp,off); }
    if (lane==0) atomicAdd(&acc[0],(double)(-logf(sp/su)));
}

__global__ void k_fin(const double* __restrict__ acc, float* __restrict__ out){
    out[0]=(float)(0.5*acc[0]/128.0);
    out[1]=(float)(0.5*acc[1]/6400.0);
}

extern "C" void kernel_launch(void* const* d_in, const int* in_sizes, int n_in,
                              void* d_out, int out_size, void* d_ws, size_t ws_size,
                              hipStream_t stream){
    const float4* reg4=(const float4*)d_in[0];
    const float*  logits=(const float*)d_in[1];
    const float4* anc4=(const float4*)d_in[2];
    const float4* tgt4=(const float4*)d_in[3];
    const int*    labels=(const int*)d_in[4];
    char* ws=(char*)d_ws;
    double*   acc   =(double*)(ws+OFF_ACC);
    float*    t2f   =(float*)(ws+OFF_T2);
    unsigned* gmask =(unsigned*)(ws+OFF_GMASK);
    int*      gcnt  =(int*)(ws+OFF_CNT);
    int*      ccnt  =(int*)(ws+OFF_CCNT);
    unsigned* ghist =(unsigned*)(ws+OFF_HIST);
    float*    candv =(float*)(ws+OFF_CANDV);
    int*      candi =(int*)(ws+OFF_CANDI);
    unsigned* clist =(unsigned*)(ws+OFF_CLIST);

    k_pre<<<64,256,0,stream>>>((unsigned*)ws,labels,gmask);
    k_iou_neg<<<NNEG+NIOU,256,0,stream>>>(anc4,reg4,tgt4,(const float4*)logits,
                                          (unsigned*)t2f,ghist,ccnt,clist,acc);
    k_candthr<<<dim3(NCH,BB),256,0,stream>>>(anc4,tgt4,ghist,gcnt,candv,candi);
    k_selcorr<<<NBG+256,256,0,stream>>>(anc4,reg4,tgt4,logits,labels,gcnt,candv,candi,
                                        gmask,t2f,ccnt,clist,acc);
    k_fin<<<1,1,0,stream>>>(acc,(float*)d_out);
}